// Round 9
// baseline (148.038 us; speedup 1.0000x reference)
//
#include <hip/hip_runtime.h>

#define NB    16
#define CIN   16
#define COUT  32
#define DIN   32
#define DOUT  30

typedef __attribute__((ext_vector_type(8)))  short        short8;
typedef __attribute__((ext_vector_type(4)))  unsigned int uint4v;
typedef __attribute__((ext_vector_type(16))) float        f32x16;

// ws layout (bytes):
//   [0      .. 55296)      : W A-fragments, bf16 hi then lo (27*64*16 * 2)
//   [57344  .. 57344+32MB) : x as bf16 hi/lo chunks (repack_x), if ws_size permits
#define XWS_OFS_SHORTS   28672        // 57344 B
#define XWS_PART_SHORTS  8388608      // 16 MB per part (hi, lo)
#define WS_NEED          (57344 + 2ull * 16 * 1024 * 1024)

static __device__ __forceinline__ unsigned short f2bf_rne(float f) {
    unsigned int u = __builtin_bit_cast(unsigned int, f);
    u += 0x7fffu + ((u >> 16) & 1u);
    return (unsigned short)(u >> 16);
}
static __device__ __forceinline__ float bf2f(unsigned short s) {
    unsigned int u = ((unsigned int)s) << 16;
    return __builtin_bit_cast(float, u);
}
// packed f32x2 -> bf16x2 (RNE), src0 -> low half
static __device__ __forceinline__ unsigned int cvt_pk_bf16(float a, float b) {
    unsigned int r;
    asm("v_cvt_pk_bf16_f32 %0, %1, %2" : "=v"(r) : "v"(a), "v"(b));
    return r;
}
// async global->LDS, 16B per lane; lds dst = uniform base + lane*16.
// aux=2 sets the NT/streaming cache-policy bit: staged x is consumed from LDS only,
// so keep it OUT of L1 (protect the A-fragment table's residency).
static __device__ __forceinline__ void gload_lds16_nt(const short* g, short* l) {
    __builtin_amdgcn_global_load_lds(
        (const __attribute__((address_space(1))) void*)g,
        (__attribute__((address_space(3))) void*)l, 16, 0, 2);
}
static __device__ __forceinline__ void gload_lds16(const short* g, short* l) {
    __builtin_amdgcn_global_load_lds(
        (const __attribute__((address_space(1))) void*)g,
        (__attribute__((address_space(3))) void*)l, 16, 0, 0);
}

// Kernel 1: repack W[Cout][Cin][3][3][3] fp32 into MFMA A-fragment layout, bf16 hi/lo split.
__global__ __launch_bounds__(64) void repack_w(const float* __restrict__ wgt,
                                               short* __restrict__ ws) {
    const int s  = blockIdx.x;    // 0..26  (kd*9+kh*3+kw)
    const int l  = threadIdx.x;   // 0..63
    const int co  = l & 31;
    const int ci0 = (l >> 5) * 8;
    short8 vh, vl;
#pragma unroll
    for (int j = 0; j < 8; ++j) {
        float f = wgt[co * (CIN * 27) + (ci0 + j) * 27 + s];
        unsigned short h = f2bf_rne(f);
        vh[j] = (short)h;
        vl[j] = (short)f2bf_rne(f - bf2f(h));
    }
    ((short8*)ws)[s * 64 + l]            = vh;
    ((short8*)ws)[27 * 64 + s * 64 + l]  = vl;
}

// Kernel 1b: repack x[b][ci][d][h][w] fp32 -> bf16 hi/lo chunks.
// Per row-plane rp=(b*32+d)*32+h: 64 chunks (hi8*32+w), each 8 ci x bf16 = 16B.
__global__ __launch_bounds__(256) void repack_x(const float* __restrict__ x,
                                                short* __restrict__ xws) {
    const int rp  = blockIdx.x * 4 + (threadIdx.x >> 6);   // 0..16383
    const int l   = threadIdx.x & 63;
    const int hi8 = l >> 5, w = l & 31;
    const int b   = rp >> 10;
    const int dh  = rp & 1023;                              // d*32+h
    const int gbase = b * (CIN * 32768) + hi8 * 8 * 32768 + dh * 32 + w;
    float f[8];
#pragma unroll
    for (int j = 0; j < 8; ++j) f[j] = x[gbase + j * 32768];
    uint4v vh, vl;
#pragma unroll
    for (int j = 0; j < 8; j += 2) {
        unsigned int hp = cvt_pk_bf16(f[j], f[j + 1]);
        float b0 = __builtin_bit_cast(float, hp << 16);
        float b1 = __builtin_bit_cast(float, hp & 0xffff0000u);
        unsigned int lp = cvt_pk_bf16(f[j] - b0, f[j + 1] - b1);
        vh[j >> 1] = hp;
        vl[j >> 1] = lp;
    }
    ((uint4v*)xws)[rp * 64 + l]               = vh;
    ((uint4v*)xws)[1048576 + rp * 64 + l]     = vl;
}

// Main kernel v8: identical structure to v7 (8-wave d-quad block, 72 KB LDS, two-pass
// A-term split), plus cache-policy isolation of the A-table:
//   - x staging uses NT loads (bypass/evict-first in L1),
//   - output stores are non-temporal,
// so the per-pass 27.6 KB A-table can actually stay L1-resident.
__global__ __launch_bounds__(512, 4) void conv3d_mfma_v8(
    const short* __restrict__ xws,
    const short* __restrict__ wsA,
    const float* __restrict__ cbias,
    const float* __restrict__ scal,
    const float* __restrict__ bpar,
    float* __restrict__ out)
{
    __shared__ __align__(16) short sx[2 * 18432];   // hi at 0, lo at +18432 shorts (72 KB)
    __shared__ float sp[96];

    const int htile = blockIdx.x;   // 0..7
    const int dquad = blockIdx.y;   // 0..7
    const int b     = blockIdx.z;   // 0..15

    const int tid  = threadIdx.x;
    const int ww   = tid >> 6;      // 0..7
    const int wd   = ww >> 2;       // 0..1
    const int wy   = ww & 3;        // 0..3
    const int lane = tid & 63;

    if (tid < 32) {
        sp[tid]      = cbias[tid];
        sp[32 + tid] = scal[tid];
        sp[64 + tid] = bpar[tid];
    }

    const int h0 = htile * 4;
    const int d0 = dquad * 4;

    // ---- stage 36 row-planes (6 planes x 6 rows), hi+lo, async NT global_load_lds ----
#pragma unroll
    for (int t = 0; t < 5; ++t) {
        const int rpl = ww + t * 8;               // 0..39; use 0..35 = dz*6+row
        if (rpl < 36) {
            const int dz  = rpl / 6;
            const int row = rpl - dz * 6;
            int d_in = d0 + dz; if (d_in > 31) d_in = 31;   // dquad 7 halo clamp
            int h_in = h0 + row; if (h_in > 31) h_in = 31;  // htile 7 halo clamp
            const int grp = (b * 32 + d_in) * 32 + h_in;
            gload_lds16_nt(xws + (size_t)grp * 512 + lane * 8, sx + rpl * 512);
            gload_lds16_nt(xws + XWS_PART_SHORTS + (size_t)grp * 512 + lane * 8,
                           sx + 18432 + rpl * 512);
        }
    }
    __syncthreads();   // drains vmcnt(0) before barrier

    const int h   = h0 + wy;
    const int dw0 = d0 + 2 * wd;
    if (h >= DOUT || dw0 >= DOUT) return;    // only barrier above; safe to exit

    const int n  = lane & 31;   // output w (30 valid + 2 pad)
    const int hi = lane >> 5;

    // per-kw LDS base pointers (shorts); dz/kh/lo fold into immediate offsets
    const short* pb[3];
#pragma unroll
    for (int kw = 0; kw < 3; ++kw) {
        int wc = n + kw; if (wc > 31) wc = 31;   // pad lanes clamp (cols >=30 discarded)
        pb[kw] = sx + wd * 6144 + wy * 512 + hi * 256 + wc * 8;
    }

    f32x16 acc0, acc1;
#pragma unroll
    for (int i = 0; i < 16; ++i) { acc0[i] = 0.0f; acc1[i] = 0.0f; }

    const short8* wa = (const short8*)wsA;

    // ================= pass H: ah*bh + ah*bl (hi A-table, 27.6 KB, L1-resident) =========
#pragma unroll
    for (int e = 0; e < 9; ++e) {
        const int kh = e / 3, kw = e - kh * 3;
        short8 Ah0 = wa[(0 * 9 + e) * 64 + lane];
        short8 Ah1 = wa[(1 * 9 + e) * 64 + lane];
        short8 Ah2 = wa[(2 * 9 + e) * 64 + lane];

        const short* base = pb[kw] + kh * 512;
        // B depth-1 prefetch across dz
        short8 bh = *(const short8*)(base);
        short8 bl = *(const short8*)(base + 18432);
#pragma unroll
        for (int dz = 0; dz < 4; ++dz) {
            const short8 cbh = bh, cbl = bl;
            if (dz < 3) {
                bh = *(const short8*)(base + (dz + 1) * 3072);
                bl = *(const short8*)(base + 18432 + (dz + 1) * 3072);
            }
            __builtin_amdgcn_s_setprio(1);
            if (dz < 3) {   // tile0: kd = dz
                const short8 ah = (dz == 0) ? Ah0 : (dz == 1) ? Ah1 : Ah2;
                acc0 = __builtin_amdgcn_mfma_f32_32x32x16_bf16(ah, cbh, acc0, 0, 0, 0);
                acc0 = __builtin_amdgcn_mfma_f32_32x32x16_bf16(ah, cbl, acc0, 0, 0, 0);
            }
            if (dz > 0) {   // tile1: kd = dz-1
                const short8 ah = (dz == 1) ? Ah0 : (dz == 2) ? Ah1 : Ah2;
                acc1 = __builtin_amdgcn_mfma_f32_32x32x16_bf16(ah, cbh, acc1, 0, 0, 0);
                acc1 = __builtin_amdgcn_mfma_f32_32x32x16_bf16(ah, cbl, acc1, 0, 0, 0);
            }
            __builtin_amdgcn_s_setprio(0);
        }
    }

    // ================= pass L: al*bh (lo A-table, 27.6 KB, L1-resident) =================
#pragma unroll
    for (int e = 0; e < 9; ++e) {
        const int kh = e / 3, kw = e - kh * 3;
        short8 Al0 = wa[1728 + (0 * 9 + e) * 64 + lane];
        short8 Al1 = wa[1728 + (1 * 9 + e) * 64 + lane];
        short8 Al2 = wa[1728 + (2 * 9 + e) * 64 + lane];

        const short* base = pb[kw] + kh * 512;
        short8 bh = *(const short8*)(base);
#pragma unroll
        for (int dz = 0; dz < 4; ++dz) {
            const short8 cbh = bh;
            if (dz < 3) bh = *(const short8*)(base + (dz + 1) * 3072);
            __builtin_amdgcn_s_setprio(1);
            if (dz < 3) {   // tile0
                const short8 al = (dz == 0) ? Al0 : (dz == 1) ? Al1 : Al2;
                acc0 = __builtin_amdgcn_mfma_f32_32x32x16_bf16(al, cbh, acc0, 0, 0, 0);
            }
            if (dz > 0) {   // tile1
                const short8 al = (dz == 1) ? Al0 : (dz == 2) ? Al1 : Al2;
                acc1 = __builtin_amdgcn_mfma_f32_32x32x16_bf16(al, cbh, acc1, 0, 0, 0);
            }
            __builtin_amdgcn_s_setprio(0);
        }
    }

    // ---- epilogue: bias, tanh*scale, *bp, sigmoid; NT stores (never re-read) ----
    if (n < DOUT) {
        const int obase = b * (COUT * DOUT * DOUT * DOUT)
                        + dw0 * (DOUT * DOUT) + h * DOUT + n;
#pragma unroll
        for (int r = 0; r < 16; ++r) {
            const int co = (r & 3) + 8 * (r >> 2) + 4 * hi;
            const float cb = sp[co], sc = sp[32 + co], bp = sp[64 + co];
            {
                float y  = acc0[r] + cb;
                float t  = y * sc;
                float th = 1.0f - 2.0f / (__expf(2.0f * t) + 1.0f);
                float z  = th * bp;
                __builtin_nontemporal_store(1.0f / (1.0f + __expf(-z)),
                                            &out[obase + co * (DOUT * DOUT * DOUT)]);
            }
            {
                float y  = acc1[r] + cb;
                float t  = y * sc;
                float th = 1.0f - 2.0f / (__expf(2.0f * t) + 1.0f);
                float z  = th * bp;
                __builtin_nontemporal_store(1.0f / (1.0f + __expf(-z)),
                                            &out[obase + (DOUT * DOUT) + co * (DOUT * DOUT * DOUT)]);
            }
        }
    }
}

// Fallback (ws too small): v1, in-kernel conversion staging (passing baseline).
__global__ __launch_bounds__(512) void conv3d_mfma_v1(
    const float* __restrict__ x,
    const short* __restrict__ wsA,
    const float* __restrict__ cbias,
    const float* __restrict__ scal,
    const float* __restrict__ bpar,
    float* __restrict__ out)
{
    __shared__ __align__(16) short sx[2 * 12288];
    __shared__ float sp[96];

    const int htile = blockIdx.x;
    const int dpair = blockIdx.y;
    const int b     = blockIdx.z;

    const int tid  = threadIdx.x;
    const int ww   = tid >> 6;
    const int wd   = ww >> 2;
    const int wy   = ww & 3;
    const int lane = tid & 63;

    if (tid < 32) {
        sp[tid]      = cbias[tid];
        sp[32 + tid] = scal[tid];
        sp[64 + tid] = bpar[tid];
    }

    const int h0 = htile * 4;
    const int d0 = dpair * 2;

    const int xb = b * (CIN * DIN * DIN * DIN);
    for (int c = tid; c < 1536; c += 512) {
        const int w   = c & 31;
        const int hi8 = (c >> 5) & 1;
        const int rr  = c >> 6;
        const int dz  = rr / 6;
        const int row = rr - dz * 6;
        int h_in = h0 + row; if (h_in > 31) h_in = 31;
        const int gbase = xb + (hi8 * 8) * (DIN * DIN * DIN)
                        + (d0 + dz) * (DIN * DIN) + h_in * DIN + w;
        float f[8];
#pragma unroll
        for (int j = 0; j < 8; ++j) f[j] = x[gbase + j * (DIN * DIN * DIN)];
        uint4v vh, vl;
#pragma unroll
        for (int j = 0; j < 8; j += 2) {
            unsigned int hp = cvt_pk_bf16(f[j], f[j + 1]);
            float b0 = __builtin_bit_cast(float, hp << 16);
            float b1 = __builtin_bit_cast(float, hp & 0xffff0000u);
            unsigned int lp = cvt_pk_bf16(f[j] - b0, f[j + 1] - b1);
            vh[j >> 1] = hp;
            vl[j >> 1] = lp;
        }
        const int idx = rr * 64 + hi8 * 32 + w;
        *(uint4v*)(sx + idx * 8)         = vh;
        *(uint4v*)(sx + 12288 + idx * 8) = vl;
    }
    __syncthreads();

    const int h = h0 + wy;
    if (h >= DOUT) return;
    const int d = d0 + wd;

    const int n  = lane & 31;
    const int hi = lane >> 5;

    int wofs[3];
#pragma unroll
    for (int kw = 0; kw < 3; ++kw) {
        int wc = n + kw; if (wc > 31) wc = 31;
        wofs[kw] = hi * 256 + wc * 8;
    }

    f32x16 acc;
#pragma unroll
    for (int i = 0; i < 16; ++i) acc[i] = 0.0f;

    const short8* wa = (const short8*)wsA;
#pragma unroll
    for (int kd = 0; kd < 3; ++kd) {
#pragma unroll
        for (int kh = 0; kh < 3; ++kh) {
            const int rbase = ((wd + kd) * 6 + wy + kh) * 512;
#pragma unroll
            for (int kw = 0; kw < 3; ++kw) {
                const int s = kd * 9 + kh * 3 + kw;
                short8 ah = wa[s * 64 + lane];
                short8 al = wa[1728 + s * 64 + lane];
                short8 bh = *(const short8*)(sx + rbase + wofs[kw]);
                short8 bl = *(const short8*)(sx + 12288 + rbase + wofs[kw]);
                acc = __builtin_amdgcn_mfma_f32_32x32x16_bf16(ah, bh, acc, 0, 0, 0);
                acc = __builtin_amdgcn_mfma_f32_32x32x16_bf16(ah, bl, acc, 0, 0, 0);
                acc = __builtin_amdgcn_mfma_f32_32x32x16_bf16(al, bh, acc, 0, 0, 0);
            }
        }
    }

    if (n < DOUT) {
        const int obase = b * (COUT * DOUT * DOUT * DOUT)
                        + d * (DOUT * DOUT) + h * DOUT + n;
#pragma unroll
        for (int r = 0; r < 16; ++r) {
            const int co = (r & 3) + 8 * (r >> 2) + 4 * hi;
            float y  = acc[r] + sp[co];
            float t  = y * sp[32 + co];
            float th = 1.0f - 2.0f / (__expf(2.0f * t) + 1.0f);
            float z  = th * sp[64 + co];
            float rr = 1.0f / (1.0f + __expf(-z));
            out[obase + co * (DOUT * DOUT * DOUT)] = rr;
        }
    }
}

extern "C" void kernel_launch(void* const* d_in, const int* in_sizes, int n_in,
                              void* d_out, int out_size, void* d_ws, size_t ws_size,
                              hipStream_t stream) {
    const float* x     = (const float*)d_in[0];
    const float* wgt   = (const float*)d_in[1];
    const float* cbias = (const float*)d_in[2];
    const float* scal  = (const float*)d_in[3];
    const float* bpar  = (const float*)d_in[4];
    float* out = (float*)d_out;
    short* ws  = (short*)d_ws;

    hipLaunchKernelGGL(repack_w, dim3(27), dim3(64), 0, stream, wgt, ws);

    if (ws_size >= WS_NEED) {
        short* xws = ws + XWS_OFS_SHORTS;
        hipLaunchKernelGGL(repack_x, dim3(4096), dim3(256), 0, stream, x, xws);
        hipLaunchKernelGGL(conv3d_mfma_v8, dim3(8, 8, NB), dim3(512), 0, stream,
                           xws, ws, cbias, scal, bpar, out);
    } else {
        hipLaunchKernelGGL(conv3d_mfma_v1, dim3(8, 15, NB), dim3(512), 0, stream,
                           x, ws, cbias, scal, bpar, out);
    }
}

// Round 12
// 134.530 us; speedup vs baseline: 1.1004x; 1.1004x over previous
//
#include <hip/hip_runtime.h>

#define NB    16
#define CIN   16
#define COUT  32
#define DIN   32
#define DOUT  30

typedef __attribute__((ext_vector_type(8)))  short        short8;
typedef __attribute__((ext_vector_type(4)))  unsigned int uint4v;
typedef __attribute__((ext_vector_type(16))) float        f32x16;

static __device__ __forceinline__ unsigned short f2bf_rne(float f) {
    unsigned int u = __builtin_bit_cast(unsigned int, f);
    u += 0x7fffu + ((u >> 16) & 1u);
    return (unsigned short)(u >> 16);
}
static __device__ __forceinline__ float bf2f(unsigned short s) {
    unsigned int u = ((unsigned int)s) << 16;
    return __builtin_bit_cast(float, u);
}
// packed f32x2 -> bf16x2 (RNE), src0 -> low half
static __device__ __forceinline__ unsigned int cvt_pk_bf16(float a, float b) {
    unsigned int r;
    asm("v_cvt_pk_bf16_f32 %0, %1, %2" : "=v"(r) : "v"(a), "v"(b));
    return r;
}

// Kernel 1: repack W[Cout][Cin][3][3][3] fp32 into MFMA A-fragment layout, bf16 hi/lo split.
// ws: hi at chunk [s*64+l], lo at chunk [1728 + s*64+l]; chunk = 16 B (short8).
__global__ __launch_bounds__(64) void repack_w(const float* __restrict__ wgt,
                                               short* __restrict__ ws) {
    const int s  = blockIdx.x;    // 0..26  (kd*9+kh*3+kw)
    const int l  = threadIdx.x;   // 0..63
    const int co  = l & 31;
    const int ci0 = (l >> 5) * 8;
    short8 vh, vl;
#pragma unroll
    for (int j = 0; j < 8; ++j) {
        float f = wgt[co * (CIN * 27) + (ci0 + j) * 27 + s];
        unsigned short h = f2bf_rne(f);
        vh[j] = (short)h;
        vl[j] = (short)f2bf_rne(f - bf2f(h));
    }
    ((short8*)ws)[s * 64 + l]            = vh;
    ((short8*)ws)[27 * 64 + s * 64 + l]  = vl;
}

// Main kernel v10: v4 geometry + in-kernel x conversion staging (repack_x eliminated).
// Block (htile, dquad, b) = 8 waves (512 thr); wave (wd, wy) computes output rows
// (b, :, d0+2wd + {0,1}, h0+wy, :) via the d-pair register-blocked 3-term loop.
// LDS x-tile: 6 planes x 6 rows x [2 cichunk x 32 w x 8 ci] bf16 hi/lo = 72 KB.
// Staging: each thread converts fp32 x -> bf16 hi/lo chunks directly into LDS
// (proven v1 staging; benched equal to the gload_lds path at equal geometry).
__global__ __launch_bounds__(512, 4) void conv3d_mfma_v10(
    const float* __restrict__ x,
    const short* __restrict__ wsA,
    const float* __restrict__ cbias,
    const float* __restrict__ scal,
    const float* __restrict__ bpar,
    float* __restrict__ out)
{
    __shared__ __align__(16) short sx[2 * 18432];   // hi at 0, lo at +18432 shorts (72 KB)
    __shared__ float sp[96];

    const int htile = blockIdx.x;   // 0..7
    const int dquad = blockIdx.y;   // 0..7
    const int b     = blockIdx.z;   // 0..15

    const int tid  = threadIdx.x;
    const int ww   = tid >> 6;      // 0..7
    const int wd   = ww >> 2;       // 0..1
    const int wy   = ww & 3;        // 0..3
    const int lane = tid & 63;

    if (tid < 32) {
        sp[tid]      = cbias[tid];
        sp[32 + tid] = scal[tid];
        sp[64 + tid] = bpar[tid];
    }

    const int h0 = htile * 4;
    const int d0 = dquad * 4;

    // ---- stage 36 row-planes (6 planes x 6 rows): fp32 -> bf16 hi/lo into LDS ----
    // chunk-half c = rr*64 + hi8*32 + w (rr = dz*6+row, 0..35): 8 ci values -> vh+vl.
    const int xb = b * (CIN * DIN * DIN * DIN);
    for (int c = tid; c < 2304; c += 512) {
        const int w   = c & 31;
        const int hi8 = (c >> 5) & 1;
        const int rr  = c >> 6;         // dz*6+row, 0..35
        const int dz  = rr / 6;
        const int row = rr - dz * 6;
        int d_in = d0 + dz; if (d_in > 31) d_in = 31;   // dquad 7 halo clamp (unused tiles)
        int h_in = h0 + row; if (h_in > 31) h_in = 31;  // htile 7 halo clamp (rows unused)
        const int gbase = xb + (hi8 * 8) * (DIN * DIN * DIN)
                        + d_in * (DIN * DIN) + h_in * DIN + w;
        float f[8];
#pragma unroll
        for (int j = 0; j < 8; ++j) f[j] = x[gbase + j * (DIN * DIN * DIN)];
        uint4v vh, vl;
#pragma unroll
        for (int j = 0; j < 8; j += 2) {
            unsigned int hp = cvt_pk_bf16(f[j], f[j + 1]);
            float b0 = __builtin_bit_cast(float, hp << 16);
            float b1 = __builtin_bit_cast(float, hp & 0xffff0000u);
            unsigned int lp = cvt_pk_bf16(f[j] - b0, f[j + 1] - b1);
            vh[j >> 1] = hp;
            vl[j >> 1] = lp;
        }
        const int idx = rr * 64 + hi8 * 32 + w;          // 16B units
        *(uint4v*)(sx + idx * 8)         = vh;
        *(uint4v*)(sx + 18432 + idx * 8) = vl;
    }
    __syncthreads();

    const int h   = h0 + wy;
    const int dw0 = d0 + 2 * wd;
    if (h >= DOUT || dw0 >= DOUT) return;    // only barrier above; safe to exit

    const int n  = lane & 31;   // output w (30 valid + 2 pad)
    const int hi = lane >> 5;

    // per-kw LDS base pointers (shorts); dz/kh/lo fold into immediate offsets
    const short* pb[3];
#pragma unroll
    for (int kw = 0; kw < 3; ++kw) {
        int wc = n + kw; if (wc > 31) wc = 31;   // pad lanes clamp (cols >=30 discarded)
        pb[kw] = sx + wd * 6144 + wy * 512 + hi * 256 + wc * 8;
    }

    f32x16 acc0, acc1;
#pragma unroll
    for (int i = 0; i < 16; ++i) { acc0[i] = 0.0f; acc1[i] = 0.0f; }

    const short8* wa = (const short8*)wsA;

    // A double-buffer: preload e=0
    short8 Ah0 = wa[0 * 64 + lane],  Ah1 = wa[9 * 64 + lane],  Ah2 = wa[18 * 64 + lane];
    short8 Al0 = wa[1728 + 0 * 64 + lane], Al1 = wa[1728 + 9 * 64 + lane],
           Al2 = wa[1728 + 18 * 64 + lane];

#pragma unroll
    for (int e = 0; e < 9; ++e) {
        const int kh = e / 3, kw = e - kh * 3;
        const int en = (e < 8) ? e + 1 : 8;
        // prefetch next-e A fragments (global; latency hidden under this e's MFMAs)
        short8 Anh0 = wa[(0 * 9 + en) * 64 + lane];
        short8 Anh1 = wa[(1 * 9 + en) * 64 + lane];
        short8 Anh2 = wa[(2 * 9 + en) * 64 + lane];
        short8 Anl0 = wa[1728 + (0 * 9 + en) * 64 + lane];
        short8 Anl1 = wa[1728 + (1 * 9 + en) * 64 + lane];
        short8 Anl2 = wa[1728 + (2 * 9 + en) * 64 + lane];

        const short* base = pb[kw] + kh * 512;
        // B depth-1 prefetch across dz
        short8 bh = *(const short8*)(base);
        short8 bl = *(const short8*)(base + 18432);
#pragma unroll
        for (int dz = 0; dz < 4; ++dz) {
            const short8 cbh = bh, cbl = bl;
            if (dz < 3) {
                bh = *(const short8*)(base + (dz + 1) * 3072);
                bl = *(const short8*)(base + 18432 + (dz + 1) * 3072);
            }
            __builtin_amdgcn_s_setprio(1);
            if (dz < 3) {   // tile0: kd = dz
                const short8 ah = (dz == 0) ? Ah0 : (dz == 1) ? Ah1 : Ah2;
                const short8 al = (dz == 0) ? Al0 : (dz == 1) ? Al1 : Al2;
                acc0 = __builtin_amdgcn_mfma_f32_32x32x16_bf16(ah, cbh, acc0, 0, 0, 0);
                acc0 = __builtin_amdgcn_mfma_f32_32x32x16_bf16(ah, cbl, acc0, 0, 0, 0);
                acc0 = __builtin_amdgcn_mfma_f32_32x32x16_bf16(al, cbh, acc0, 0, 0, 0);
            }
            if (dz > 0) {   // tile1: kd = dz-1
                const short8 ah = (dz == 1) ? Ah0 : (dz == 2) ? Ah1 : Ah2;
                const short8 al = (dz == 1) ? Al0 : (dz == 2) ? Al1 : Al2;
                acc1 = __builtin_amdgcn_mfma_f32_32x32x16_bf16(ah, cbh, acc1, 0, 0, 0);
                acc1 = __builtin_amdgcn_mfma_f32_32x32x16_bf16(ah, cbl, acc1, 0, 0, 0);
                acc1 = __builtin_amdgcn_mfma_f32_32x32x16_bf16(al, cbh, acc1, 0, 0, 0);
            }
            __builtin_amdgcn_s_setprio(0);
        }
        Ah0 = Anh0; Ah1 = Anh1; Ah2 = Anh2;
        Al0 = Anl0; Al1 = Anl1; Al2 = Anl2;
    }

    // ---- epilogue: bias, tanh*scale, *bp, sigmoid; C/D map: co=(r&3)+8*(r>>2)+4*hi ----
    if (n < DOUT) {
        const int obase = b * (COUT * DOUT * DOUT * DOUT)
                        + dw0 * (DOUT * DOUT) + h * DOUT + n;
#pragma unroll
        for (int r = 0; r < 16; ++r) {
            const int co = (r & 3) + 8 * (r >> 2) + 4 * hi;
            const float cb = sp[co], sc = sp[32 + co], bp = sp[64 + co];
            {
                float y  = acc0[r] + cb;
                float t  = y * sc;
                float th = 1.0f - 2.0f / (__expf(2.0f * t) + 1.0f);
                float z  = th * bp;
                out[obase + co * (DOUT * DOUT * DOUT)] = 1.0f / (1.0f + __expf(-z));
            }
            {
                float y  = acc1[r] + cb;
                float t  = y * sc;
                float th = 1.0f - 2.0f / (__expf(2.0f * t) + 1.0f);
                float z  = th * bp;
                out[obase + (DOUT * DOUT) + co * (DOUT * DOUT * DOUT)] = 1.0f / (1.0f + __expf(-z));
            }
        }
    }
}

extern "C" void kernel_launch(void* const* d_in, const int* in_sizes, int n_in,
                              void* d_out, int out_size, void* d_ws, size_t ws_size,
                              hipStream_t stream) {
    const float* x     = (const float*)d_in[0];
    const float* wgt   = (const float*)d_in[1];
    const float* cbias = (const float*)d_in[2];
    const float* scal  = (const float*)d_in[3];
    const float* bpar  = (const float*)d_in[4];
    float* out = (float*)d_out;
    short* ws  = (short*)d_ws;   // needs only 55296 B (W A-fragments)

    hipLaunchKernelGGL(repack_w, dim3(27), dim3(64), 0, stream, wgt, ws);
    hipLaunchKernelGGL(conv3d_mfma_v10, dim3(8, 8, NB), dim3(512), 0, stream,
                       x, ws, cbias, scal, bpar, out);
}

// Round 13
// 134.132 us; speedup vs baseline: 1.1037x; 1.0030x over previous
//
#include <hip/hip_runtime.h>

#define NB    16
#define CIN   16
#define COUT  32
#define DIN   32
#define DOUT  30

typedef __attribute__((ext_vector_type(8)))  short        short8;
typedef __attribute__((ext_vector_type(4)))  unsigned int uint4v;
typedef __attribute__((ext_vector_type(16))) float        f32x16;

static __device__ __forceinline__ unsigned short f2bf_rne(float f) {
    unsigned int u = __builtin_bit_cast(unsigned int, f);
    u += 0x7fffu + ((u >> 16) & 1u);
    return (unsigned short)(u >> 16);
}
static __device__ __forceinline__ float bf2f(unsigned short s) {
    unsigned int u = ((unsigned int)s) << 16;
    return __builtin_bit_cast(float, u);
}
// packed f32x2 -> bf16x2 (RNE), src0 -> low half
static __device__ __forceinline__ unsigned int cvt_pk_bf16(float a, float b) {
    unsigned int r;
    asm("v_cvt_pk_bf16_f32 %0, %1, %2" : "=v"(r) : "v"(a), "v"(b));
    return r;
}

// Kernel 1: repack W[Cout][Cin][3][3][3] fp32 into MFMA A-fragment layout, bf16 hi/lo split.
// ws: hi at chunk [s*64+l], lo at chunk [1728 + s*64+l]; chunk = 16 B (short8).
__global__ __launch_bounds__(64) void repack_w(const float* __restrict__ wgt,
                                               short* __restrict__ ws) {
    const int s  = blockIdx.x;    // 0..26  (kd*9+kh*3+kw)
    const int l  = threadIdx.x;   // 0..63
    const int co  = l & 31;
    const int ci0 = (l >> 5) * 8;
    short8 vh, vl;
#pragma unroll
    for (int j = 0; j < 8; ++j) {
        float f = wgt[co * (CIN * 27) + (ci0 + j) * 27 + s];
        unsigned short h = f2bf_rne(f);
        vh[j] = (short)h;
        vl[j] = (short)f2bf_rne(f - bf2f(h));
    }
    ((short8*)ws)[s * 64 + l]            = vh;
    ((short8*)ws)[27 * 64 + s * 64 + l]  = vl;
}

// Main kernel v11: v10 (8-wave d-quad block, 72 KB LDS, in-kernel fp32->bf16 hi/lo
// staging, dual-acc merged 3-term loop) + residual latency sweep:
//   - e=0 A-fragment preloads hoisted ABOVE the staging barrier (L2 latency drains
//     during the barrier wait instead of serializing after it),
//   - epilogue params read directly from global (L1 broadcast; sp[] LDS path removed).
__global__ __launch_bounds__(512, 4) void conv3d_mfma_v11(
    const float* __restrict__ x,
    const short* __restrict__ wsA,
    const float* __restrict__ cbias,
    const float* __restrict__ scal,
    const float* __restrict__ bpar,
    float* __restrict__ out)
{
    __shared__ __align__(16) short sx[2 * 18432];   // hi at 0, lo at +18432 shorts (72 KB)

    const int htile = blockIdx.x;   // 0..7
    const int dquad = blockIdx.y;   // 0..7
    const int b     = blockIdx.z;   // 0..15

    const int tid  = threadIdx.x;
    const int ww   = tid >> 6;      // 0..7
    const int wd   = ww >> 2;       // 0..1
    const int wy   = ww & 3;        // 0..3
    const int lane = tid & 63;

    const int h0 = htile * 4;
    const int d0 = dquad * 4;

    // ---- stage 36 row-planes (6 planes x 6 rows): fp32 -> bf16 hi/lo into LDS ----
    // chunk-half c = rr*64 + hi8*32 + w (rr = dz*6+row, 0..35): 8 ci values -> vh+vl.
    const int xb = b * (CIN * DIN * DIN * DIN);
    for (int c = tid; c < 2304; c += 512) {
        const int w   = c & 31;
        const int hi8 = (c >> 5) & 1;
        const int rr  = c >> 6;         // dz*6+row, 0..35
        const int dz  = rr / 6;
        const int row = rr - dz * 6;
        int d_in = d0 + dz; if (d_in > 31) d_in = 31;   // dquad 7 halo clamp (unused tiles)
        int h_in = h0 + row; if (h_in > 31) h_in = 31;  // htile 7 halo clamp (rows unused)
        const int gbase = xb + (hi8 * 8) * (DIN * DIN * DIN)
                        + d_in * (DIN * DIN) + h_in * DIN + w;
        float f[8];
#pragma unroll
        for (int j = 0; j < 8; ++j) f[j] = x[gbase + j * (DIN * DIN * DIN)];
        uint4v vh, vl;
#pragma unroll
        for (int j = 0; j < 8; j += 2) {
            unsigned int hp = cvt_pk_bf16(f[j], f[j + 1]);
            float b0 = __builtin_bit_cast(float, hp << 16);
            float b1 = __builtin_bit_cast(float, hp & 0xffff0000u);
            unsigned int lp = cvt_pk_bf16(f[j] - b0, f[j + 1] - b1);
            vh[j >> 1] = hp;
            vl[j >> 1] = lp;
        }
        const int idx = rr * 64 + hi8 * 32 + w;          // 16B units
        *(uint4v*)(sx + idx * 8)         = vh;
        *(uint4v*)(sx + 18432 + idx * 8) = vl;
    }

    // ---- e=0 A-fragment preloads issued BEFORE the barrier: their L2 latency
    //      drains during the barrier wait (they read wsA, independent of staging) ----
    const short8* wa = (const short8*)wsA;
    short8 Ah0 = wa[0 * 64 + lane],  Ah1 = wa[9 * 64 + lane],  Ah2 = wa[18 * 64 + lane];
    short8 Al0 = wa[1728 + 0 * 64 + lane], Al1 = wa[1728 + 9 * 64 + lane],
           Al2 = wa[1728 + 18 * 64 + lane];

    __syncthreads();

    const int h   = h0 + wy;
    const int dw0 = d0 + 2 * wd;
    if (h >= DOUT || dw0 >= DOUT) return;    // only barrier above; safe to exit

    const int n  = lane & 31;   // output w (30 valid + 2 pad)
    const int hi = lane >> 5;

    // per-kw LDS base pointers (shorts); dz/kh/lo fold into immediate offsets
    const short* pb[3];
#pragma unroll
    for (int kw = 0; kw < 3; ++kw) {
        int wc = n + kw; if (wc > 31) wc = 31;   // pad lanes clamp (cols >=30 discarded)
        pb[kw] = sx + wd * 6144 + wy * 512 + hi * 256 + wc * 8;
    }

    f32x16 acc0, acc1;
#pragma unroll
    for (int i = 0; i < 16; ++i) { acc0[i] = 0.0f; acc1[i] = 0.0f; }

#pragma unroll
    for (int e = 0; e < 9; ++e) {
        const int kh = e / 3, kw = e - kh * 3;
        const int en = (e < 8) ? e + 1 : 8;
        // prefetch next-e A fragments (global; latency hidden under this e's MFMAs)
        short8 Anh0 = wa[(0 * 9 + en) * 64 + lane];
        short8 Anh1 = wa[(1 * 9 + en) * 64 + lane];
        short8 Anh2 = wa[(2 * 9 + en) * 64 + lane];
        short8 Anl0 = wa[1728 + (0 * 9 + en) * 64 + lane];
        short8 Anl1 = wa[1728 + (1 * 9 + en) * 64 + lane];
        short8 Anl2 = wa[1728 + (2 * 9 + en) * 64 + lane];

        const short* base = pb[kw] + kh * 512;
        // B depth-1 prefetch across dz
        short8 bh = *(const short8*)(base);
        short8 bl = *(const short8*)(base + 18432);
#pragma unroll
        for (int dz = 0; dz < 4; ++dz) {
            const short8 cbh = bh, cbl = bl;
            if (dz < 3) {
                bh = *(const short8*)(base + (dz + 1) * 3072);
                bl = *(const short8*)(base + 18432 + (dz + 1) * 3072);
            }
            __builtin_amdgcn_s_setprio(1);
            if (dz < 3) {   // tile0: kd = dz
                const short8 ah = (dz == 0) ? Ah0 : (dz == 1) ? Ah1 : Ah2;
                const short8 al = (dz == 0) ? Al0 : (dz == 1) ? Al1 : Al2;
                acc0 = __builtin_amdgcn_mfma_f32_32x32x16_bf16(ah, cbh, acc0, 0, 0, 0);
                acc0 = __builtin_amdgcn_mfma_f32_32x32x16_bf16(ah, cbl, acc0, 0, 0, 0);
                acc0 = __builtin_amdgcn_mfma_f32_32x32x16_bf16(al, cbh, acc0, 0, 0, 0);
            }
            if (dz > 0) {   // tile1: kd = dz-1
                const short8 ah = (dz == 1) ? Ah0 : (dz == 2) ? Ah1 : Ah2;
                const short8 al = (dz == 1) ? Al0 : (dz == 2) ? Al1 : Al2;
                acc1 = __builtin_amdgcn_mfma_f32_32x32x16_bf16(ah, cbh, acc1, 0, 0, 0);
                acc1 = __builtin_amdgcn_mfma_f32_32x32x16_bf16(ah, cbl, acc1, 0, 0, 0);
                acc1 = __builtin_amdgcn_mfma_f32_32x32x16_bf16(al, cbh, acc1, 0, 0, 0);
            }
            __builtin_amdgcn_s_setprio(0);
        }
        Ah0 = Anh0; Ah1 = Anh1; Ah2 = Anh2;
        Al0 = Anl0; Al1 = Anl1; Al2 = Anl2;
    }

    // ---- epilogue: bias, tanh*scale, *bp, sigmoid; C/D map: co=(r&3)+8*(r>>2)+4*hi ----
    // params read directly (two L1 broadcasts per r); no LDS/barrier dependency.
    if (n < DOUT) {
        const int obase = b * (COUT * DOUT * DOUT * DOUT)
                        + dw0 * (DOUT * DOUT) + h * DOUT + n;
#pragma unroll
        for (int r = 0; r < 16; ++r) {
            const int co = (r & 3) + 8 * (r >> 2) + 4 * hi;
            const float cb = cbias[co], sc = scal[co], bp = bpar[co];
            {
                float y  = acc0[r] + cb;
                float t  = y * sc;
                float th = 1.0f - 2.0f / (__expf(2.0f * t) + 1.0f);
                float z  = th * bp;
                out[obase + co * (DOUT * DOUT * DOUT)] = 1.0f / (1.0f + __expf(-z));
            }
            {
                float y  = acc1[r] + cb;
                float t  = y * sc;
                float th = 1.0f - 2.0f / (__expf(2.0f * t) + 1.0f);
                float z  = th * bp;
                out[obase + (DOUT * DOUT) + co * (DOUT * DOUT * DOUT)] = 1.0f / (1.0f + __expf(-z));
            }
        }
    }
}

extern "C" void kernel_launch(void* const* d_in, const int* in_sizes, int n_in,
                              void* d_out, int out_size, void* d_ws, size_t ws_size,
                              hipStream_t stream) {
    const float* x     = (const float*)d_in[0];
    const float* wgt   = (const float*)d_in[1];
    const float* cbias = (const float*)d_in[2];
    const float* scal  = (const float*)d_in[3];
    const float* bpar  = (const float*)d_in[4];
    float* out = (float*)d_out;
    short* ws  = (short*)d_ws;   // needs only 55296 B (W A-fragments)

    hipLaunchKernelGGL(repack_w, dim3(27), dim3(64), 0, stream, wgt, ws);
    hipLaunchKernelGGL(conv3d_mfma_v11, dim3(8, 8, NB), dim3(512), 0, stream,
                       x, ws, cbias, scal, bpar, out);
}